// Round 14
// baseline (2174.494 us; speedup 1.0000x reference)
//
#include <hip/hip_runtime.h>
#include <math.h>

#define B_ 8
#define C_ 64
#define N_ 4096
#define K_ 20
#define O_ 64
#define CS 4          // column segments; grid = 4*16*8 = 512 blocks (2/CU)
#define TC 32         // columns per register tile (acc[TC] in VGPRs)
#define NKf 81920.0f  // N*K
#define EPS 1e-5f
#define SLOPE 0.2f

// 20-deep sorted insert (descending); register arrays (kmerge only).
#define INS20(sv, mv)                                            \
  {                                                              \
    _Pragma("unroll")                                            \
    for (int j = 19; j >= 1; --j) {                              \
      bool sh = (sv) > tv[j - 1];                                \
      bool he = (!sh) && ((sv) > tv[j]);                         \
      tv[j] = sh ? tv[j - 1] : (he ? (sv) : tv[j]);              \
      ti[j] = sh ? ti[j - 1] : (he ? (mv) : ti[j]);              \
    }                                                            \
    if ((sv) > tv[0]) { tv[0] = (sv); ti[0] = (mv); }            \
  }

// ---- Kernel A: xx = sum_c x^2, P = W1^T x, Q = (W2-W1)^T x ----
__global__ __launch_bounds__(256) void ka(const float* __restrict__ x,
                                          const float* __restrict__ W,
                                          float* __restrict__ xx,
                                          float* __restrict__ Pt,
                                          float* __restrict__ Qt) {
  __shared__ float wl[O_ * 128];
  int t = threadIdx.x;
#pragma unroll
  for (int j = 0; j < 32; ++j) wl[t + 256 * j] = W[t + 256 * j];
  __syncthreads();
  int gid = blockIdx.x * 256 + t;  // (b,n) flat, 0..32767
  int b = gid >> 12;
  int n = gid & 4095;
  const float* xb = x + (size_t)b * C_ * N_ + n;
  float xr[64];
  float sq = 0.f;
#pragma unroll
  for (int c = 0; c < 64; ++c) {
    xr[c] = xb[(size_t)c * N_];
    sq = fmaf(xr[c], xr[c], sq);
  }
  xx[gid] = sq;
  float* prow = Pt + (size_t)gid * 64;
  float* qrow = Qt + (size_t)gid * 64;
  for (int o = 0; o < 64; ++o) {
    const float4* w1 = (const float4*)&wl[o * 128];
    const float4* w2 = (const float4*)&wl[o * 128 + 64];
    float pa = 0.f, pb = 0.f, qa = 0.f, qb = 0.f;
#pragma unroll
    for (int c4 = 0; c4 < 16; c4 += 2) {
      float4 wa = w1[c4], wb = w1[c4 + 1];
      float4 va = w2[c4], vb = w2[c4 + 1];
      pa = fmaf(xr[4 * c4 + 0], wa.x, pa);
      pa = fmaf(xr[4 * c4 + 1], wa.y, pa);
      pa = fmaf(xr[4 * c4 + 2], wa.z, pa);
      pa = fmaf(xr[4 * c4 + 3], wa.w, pa);
      pb = fmaf(xr[4 * c4 + 4], wb.x, pb);
      pb = fmaf(xr[4 * c4 + 5], wb.y, pb);
      pb = fmaf(xr[4 * c4 + 6], wb.z, pb);
      pb = fmaf(xr[4 * c4 + 7], wb.w, pb);
      qa = fmaf(xr[4 * c4 + 0], va.x, qa);
      qa = fmaf(xr[4 * c4 + 1], va.y, qa);
      qa = fmaf(xr[4 * c4 + 2], va.z, qa);
      qa = fmaf(xr[4 * c4 + 3], va.w, qa);
      qb = fmaf(xr[4 * c4 + 4], vb.x, qb);
      qb = fmaf(xr[4 * c4 + 5], vb.y, qb);
      qb = fmaf(xr[4 * c4 + 6], vb.z, qb);
      qb = fmaf(xr[4 * c4 + 7], vb.w, qb);
    }
    float p = pa + pb;
    prow[o] = p;
    qrow[o] = (qa + qb) - p;
  }
}

// ===== kb v3: register-blocked column tiles (r12 units-errata redesign) =====
// ERRATA r12: FETCH/WRITE_SIZE are KB -> kb never moved GBs; it was bound by
// the compiler re-loading the row vector from L1/L2 every column instead of
// keeping it resident. Fix: per-thread hot state = acc[TC=32] column scores
// (touched by every fmac -> MUST be registers, ~50 VGPR total plan). Channels
// stream: per c one coalesced row load x[b][c][n] (L1-resident, 16KB/wave
// unique) + 8 uniform float4 column loads (each block reads its 256KB panel
// once from L2). Top-20: split b32 LDS arrays (bank=t%32, 2 lanes/bank =
// free) + register threshold; sorted shift-insert, strict compares keep
// first-seen on ties (== jax top_k lower-index rule).
__global__ __launch_bounds__(256) void kb(const float* __restrict__ x,
                                          const float* __restrict__ xx,
                                          float* __restrict__ candv,
                                          int* __restrict__ candi) {
  __shared__ float lv[20 * 256];
  __shared__ int li[20 * 256];
  int seg = blockIdx.x;  // 0..CS-1
  int rb = blockIdx.y;   // 0..15
  int b = blockIdx.z;    // 0..7
  int t = threadIdx.x;
  int n = rb * 256 + t;
#pragma unroll
  for (int j = 0; j < 20; ++j) {
    lv[j * 256 + t] = -INFINITY;
    li[j * 256 + t] = 0;
  }
  const float* xb = x + (size_t)b * C_ * N_;
  const float* xxb = xx + (size_t)b * N_;
  float rthresh = -INFINITY;
  const int m0s = seg * (N_ / CS);
  for (int m0 = m0s; m0 < m0s + N_ / CS; m0 += TC) {
    float acc[TC];
#pragma unroll
    for (int j4 = 0; j4 < TC / 4; ++j4) {  // uniform xx loads
      float4 xv4 = *(const float4*)&xxb[m0 + j4 * 4];
      acc[j4 * 4 + 0] = -xv4.x;
      acc[j4 * 4 + 1] = -xv4.y;
      acc[j4 * 4 + 2] = -xv4.z;
      acc[j4 * 4 + 3] = -xv4.w;
    }
#pragma unroll 2
    for (int c = 0; c < 64; ++c) {
      const float* xc = xb + (size_t)c * N_;
      float xv = 2.f * xc[n];  // coalesced per-lane row element
#pragma unroll
      for (int j4 = 0; j4 < TC / 4; ++j4) {
        float4 cv = *(const float4*)&xc[m0 + j4 * 4];  // uniform column vals
        acc[j4 * 4 + 0] = fmaf(xv, cv.x, acc[j4 * 4 + 0]);
        acc[j4 * 4 + 1] = fmaf(xv, cv.y, acc[j4 * 4 + 1]);
        acc[j4 * 4 + 2] = fmaf(xv, cv.z, acc[j4 * 4 + 2]);
        acc[j4 * 4 + 3] = fmaf(xv, cv.w, acc[j4 * 4 + 3]);
      }
    }
    // selection: scan the 32 register scores against cached threshold
#pragma unroll
    for (int j = 0; j < TC; ++j) {
      float s = acc[j];
      if (s > rthresh) {
        int m = m0 + j;
        int p = 19;
        while (p > 0) {
          float pv = lv[(p - 1) * 256 + t];
          if (!(pv < s)) break;  // strict: equal stays above (first-seen)
          lv[p * 256 + t] = pv;
          li[p * 256 + t] = li[(p - 1) * 256 + t];
          --p;
        }
        lv[p * 256 + t] = s;
        li[p * 256 + t] = m;
        rthresh = lv[19 * 256 + t];
      }
    }
  }
  size_t base = ((size_t)(b * N_ + n) * CS + seg) * 20;
  float* cvp = candv + base;
  int* cip = candi + base;
#pragma unroll
  for (int j = 0; j < 20; ++j) {
    cvp[j] = lv[j * 256 + t];
    cip[j] = li[j * 256 + t];
  }
}

// ---------------- Merge partial top-20 lists ----------------
__global__ __launch_bounds__(256) void kmerge(const float* __restrict__ candv,
                                              const int* __restrict__ candi,
                                              int* __restrict__ idxf) {
  int r = blockIdx.x * 256 + threadIdx.x;  // 0..32767
  const float* cv = candv + (size_t)r * (CS * 20);
  const int* ci = candi + (size_t)r * (CS * 20);
  float tv[20];
  int ti[20];
#pragma unroll
  for (int j = 0; j < 20; ++j) { tv[j] = -INFINITY; ti[j] = 0; }
  for (int seg = 0; seg < CS; ++seg) {
    const float* cvs = cv + seg * 20;
    const int* cis = ci + seg * 20;
    for (int j = 0; j < 20; ++j) {
      float s = cvs[j];
      if (!(s > tv[19])) break;  // seg list sorted desc: rest can't qualify
      int m = cis[j];
      INS20(s, m);
    }
  }
  int* op = idxf + (size_t)r * 20;
#pragma unroll
  for (int j = 0; j < 20; ++j) op[j] = ti[j];
}

// ---- Kernel D: gather P at neighbors, stats, M = max_k P + Q ----
__global__ __launch_bounds__(256) void kd(const float* __restrict__ Pt,
                                          const float* __restrict__ Qt,
                                          const int* __restrict__ idxf,
                                          float* __restrict__ Mt,
                                          float* __restrict__ S1,
                                          float* __restrict__ S2) {
  int bi = blockIdx.x;  // 0..2047
  int b = bi >> 8;
  int n0 = (bi & 255) * 16;
  int w = threadIdx.x >> 6;
  int o = threadIdx.x & 63;
  const float* Pb = Pt + (size_t)b * N_ * 64;
  float s1 = 0.f, s2 = 0.f;
#pragma unroll
  for (int r = 0; r < 4; ++r) {
    int n = n0 + w * 4 + r;
    const int* ip = idxf + (size_t)(b * N_ + n) * 20;
    float a = 0.f, bb = 0.f, mx = -INFINITY;
#pragma unroll
    for (int k = 0; k < 20; ++k) {
      int m = ip[k];
      float v = Pb[(size_t)m * 64 + o];
      a += v;
      bb = fmaf(v, v, bb);
      mx = fmaxf(mx, v);
    }
    float q = Qt[(size_t)(b * N_ + n) * 64 + o];
    Mt[(size_t)(b * N_ + n) * 64 + o] = mx + q;
    s1 += a + 20.f * q;
    s2 += bb + 2.f * q * a + 20.f * q * q;
  }
  __shared__ float red[8][64];
  red[w][o] = s1;
  red[4 + w][o] = s2;
  __syncthreads();
  if (threadIdx.x < 64) {
    float t1 = red[0][o] + red[1][o] + red[2][o] + red[3][o];
    float t2 = red[4][o] + red[5][o] + red[6][o] + red[7][o];
    atomicAdd(&S1[b * 64 + o], t1);
    atomicAdd(&S2[b * 64 + o], t2);
  }
}

// ---- Kernel E: normalize + leaky + transpose to (B,O,N) ----
__global__ __launch_bounds__(256) void ke(const float* __restrict__ Mt,
                                          const float* __restrict__ S1,
                                          const float* __restrict__ S2,
                                          float* __restrict__ out) {
  __shared__ float tile[64 * 65];
  __shared__ float mu[64], rs[64];
  int bi = blockIdx.x;  // 0..511
  int b = bi >> 6;
  int n0 = (bi & 63) * 64;
  int t = threadIdx.x;
  if (t < 64) {
    float m = S1[b * 64 + t] * (1.f / NKf);
    float v = S2[b * 64 + t] * (1.f / NKf) - m * m;
    mu[t] = m;
    rs[t] = rsqrtf(v + EPS);
  }
#pragma unroll
  for (int rr = 0; rr < 16; ++rr) {
    int f = t + rr * 256;
    int nl = f >> 6, o = f & 63;
    tile[nl * 65 + o] = Mt[((size_t)b * N_ + n0 + nl) * 64 + o];
  }
  __syncthreads();
#pragma unroll
  for (int rr = 0; rr < 16; ++rr) {
    int f = t + rr * 256;
    int o = f >> 6, nl = f & 63;
    float v = (tile[nl * 65 + o] - mu[o]) * rs[o];
    v = v > 0.f ? v : SLOPE * v;
    out[((size_t)b * 64 + o) * N_ + n0 + nl] = v;
  }
}

extern "C" void kernel_launch(void* const* d_in, const int* in_sizes, int n_in,
                              void* d_out, int out_size, void* d_ws, size_t ws_size,
                              hipStream_t stream) {
  const float* x = (const float*)d_in[0];
  const float* W = (const float*)d_in[1];
  float* out = (float*)d_out;
  float* ws = (float*)d_ws;
  float* xx = ws;                            // 32768
  float* Pt = xx + 32768;                    // 2097152  P[b][n][o]
  float* Qt = Pt + 2097152;                  // 2097152  Q[b][n][o]
  float* candv = Qt + 2097152;               // 2621440 (32768*CS*20, CS=4)
  int* candi = (int*)(candv + 2621440);      // 2621440
  int* idxf = candi + 2621440;               // 655360
  float* S1 = (float*)(idxf + 655360);       // 512
  float* S2 = S1 + 512;                      // 512
  float* Mt = candv;  // alias: candv dead after kmerge; Mt (2097152) fits

  hipLaunchKernelGGL(ka, dim3(128), dim3(256), 0, stream, x, W, xx, Pt, Qt);
  hipLaunchKernelGGL(kb, dim3(CS, 16, 8), dim3(256), 0, stream, x, xx, candv, candi);
  hipLaunchKernelGGL(kmerge, dim3(128), dim3(256), 0, stream, candv, candi, idxf);
  hipMemsetAsync(S1, 0, 1024 * sizeof(float), stream);
  hipLaunchKernelGGL(kd, dim3(2048), dim3(256), 0, stream, Pt, Qt, idxf, Mt, S1, S2);
  hipLaunchKernelGGL(ke, dim3(512), dim3(256), 0, stream, Mt, S1, S2, out);
}